// Round 8
// baseline (7224.341 us; speedup 1.0000x reference)
//
#include <hip/hip_runtime.h>
#include <cstdint>

#define B_   128
#define T_   30
#define F_   2048
#define E_   512
#define H_   512
#define A_   512
#define CD_  128
#define CV_  64
#define V_   10000
#define VP_  10112
#define NN_  49
#define G4_  2048
#define LCAP_ 31

typedef __attribute__((ext_vector_type(4))) float f32x4;
typedef _Float16 h2v __attribute__((ext_vector_type(2)));
typedef _Float16 h4v __attribute__((ext_vector_type(4)));
typedef _Float16 h8v __attribute__((ext_vector_type(8)));

__device__ __forceinline__ float fdot2f(h2v a, h2v b, float c) {
#if __has_builtin(__builtin_amdgcn_fdot2)
  return __builtin_amdgcn_fdot2(a, b, c, false);
#else
  return c + (float)a[0]*(float)b[0] + (float)a[1]*(float)b[1];
#endif
}
__device__ __forceinline__ float dot8(h8v x, h8v w, float acc) {
  acc = fdot2f((h2v){x[0],x[1]}, (h2v){w[0],w[1]}, acc);
  acc = fdot2f((h2v){x[2],x[3]}, (h2v){w[2],w[3]}, acc);
  acc = fdot2f((h2v){x[4],x[5]}, (h2v){w[4],w[5]}, acc);
  acc = fdot2f((h2v){x[6],x[7]}, (h2v){w[6],w[7]}, acc);
  return acc;
}
__device__ __forceinline__ float tanh_f(float x) {
  x = fminf(fmaxf(x, -15.f), 15.f);
  float e = __expf(2.f * x);
  return __fdividef(e - 1.f, e + 1.f);
}
__device__ __forceinline__ float sig_f(float x) {
  return __fdividef(1.f, 1.f + __expf(-x));
}

// ================= fp16 MFMA GEMM: C = A(M,K) @ B(N,K)^T (+bias) =================
template<int OUT_H, int BIAS>
__global__ __launch_bounds__(256)
void gemm_h16(const _Float16* __restrict__ A, int lda,
              const _Float16* __restrict__ B, int ldb,
              const float* __restrict__ bias,
              void* __restrict__ Cv, int ldc, int Nreal, int K) {
  __shared__ _Float16 As[128 * 32];
  __shared__ _Float16 Bs[128 * 32];
  const int tid = threadIdx.x;
  const int m0 = blockIdx.y * 128, n0 = blockIdx.x * 128;
  const int lane = tid & 63, wid = tid >> 6;
  const int wm = (wid >> 1) * 64, wn = (wid & 1) * 64;
  f32x4 acc[4][4] = {};
  const int lr = tid >> 2;
  const int lc = (tid & 3) * 8;
  const _Float16* Ag  = A + (size_t)(m0 + lr) * lda + lc;
  const _Float16* Ag2 = Ag + (size_t)64 * lda;
  const _Float16* Bg  = B + (size_t)(n0 + lr) * ldb + lc;
  const _Float16* Bg2 = Bg + (size_t)64 * ldb;
  auto* lAs = (__attribute__((address_space(3))) char*)As;
  auto* lBs = (__attribute__((address_space(3))) char*)Bs;
  const int ldst = lr * 64 + (tid & 3) * 16;
  const int ar = wm + (lane & 15);
  const int br = wn + (lane & 15);
  const int kc = (lane >> 4) * 8;
  for (int k0 = 0; k0 < K; k0 += 32) {
    __builtin_amdgcn_global_load_lds((const __attribute__((address_space(1))) char*)(Ag  + k0), lAs + ldst,        16, 0, 0);
    __builtin_amdgcn_global_load_lds((const __attribute__((address_space(1))) char*)(Ag2 + k0), lAs + 4096 + ldst, 16, 0, 0);
    __builtin_amdgcn_global_load_lds((const __attribute__((address_space(1))) char*)(Bg  + k0), lBs + ldst,        16, 0, 0);
    __builtin_amdgcn_global_load_lds((const __attribute__((address_space(1))) char*)(Bg2 + k0), lBs + 4096 + ldst, 16, 0, 0);
    __syncthreads();
    h8v af[4], bfr[4];
#pragma unroll
    for (int i = 0; i < 4; ++i) {
      af[i]  = *(const h8v*)&As[(ar + i * 16) * 32 + kc];
      bfr[i] = *(const h8v*)&Bs[(br + i * 16) * 32 + kc];
    }
#pragma unroll
    for (int i = 0; i < 4; ++i)
#pragma unroll
      for (int j = 0; j < 4; ++j)
        acc[i][j] = __builtin_amdgcn_mfma_f32_16x16x32_f16(af[i], bfr[j], acc[i][j], 0, 0, 0);
    __syncthreads();
  }
  const int orow = m0 + wm + (lane >> 4) * 4;
  const int ocol = n0 + wn + (lane & 15);
#pragma unroll
  for (int j = 0; j < 4; ++j) {
    const int col = ocol + j * 16;
    if (col >= Nreal) continue;
    const float bv = BIAS ? bias[col] : 0.f;
#pragma unroll
    for (int i = 0; i < 4; ++i) {
#pragma unroll
      for (int r = 0; r < 4; ++r) {
        const int row = orow + i * 16 + r;
        const float v = acc[i][j][r] + bv;
        if (OUT_H) ((_Float16*)Cv)[(size_t)row * ldc + col] = (_Float16)v;
        else       ((float*)Cv)[(size_t)row * ldc + col] = v;
      }
    }
  }
}

// ---------------- att_feats (B,F,49) -> att_th (B,49,F) fp16 ----------------
__global__ __launch_bounds__(256)
void transpose_att(const float* __restrict__ af, _Float16* __restrict__ att_th) {
  __shared__ float s[64 * NN_];
  const int b = blockIdx.y, f0 = blockIdx.x * 64;
  const float* src = af + (size_t)b * F_ * NN_ + (size_t)f0 * NN_;
  for (int i = threadIdx.x; i < 64 * NN_; i += 256) s[i] = src[i];
  __syncthreads();
  _Float16* dst = att_th + (size_t)b * NN_ * F_ + f0;
  for (int i = threadIdx.x; i < NN_ * 64; i += 256) {
    int n = i >> 6, j = i & 63;
    dst[(size_t)n * F_ + j] = (_Float16)s[j * NN_ + n];
  }
}

// ---------------- fp32 (strided cols) -> fp16 pack; PERM = gate-permuted rows ----------------
template<int PERM>
__global__ void pack_h16(const float* __restrict__ src, int src_ld, int c0,
                         _Float16* __restrict__ dst, int C, int R, int Rpad) {
  int i = blockIdx.x * 256 + threadIdx.x;
  if (i >= Rpad * C) return;
  int r = i / C, c = i - r * C;
  int row = PERM ? ((r & 3) * 512 + (r >> 2)) : r;
  float v = (r < R) ? src[(size_t)row * src_ld + c0 + c] : 0.f;
  dst[i] = (_Float16)v;
}

// ---------------- fp32 -> fp16 k-interleaved: dst[(k/8)*R*8 + r*8 + k%8] ----------------
template<int PERM>
__global__ void pack_ki8(const float* __restrict__ src, int src_ld, int c0,
                         _Float16* __restrict__ dst, int R, int K) {
  int i = blockIdx.x * 256 + threadIdx.x;
  if (i >= R * K) return;
  int k7 = i & 7;
  int t = i >> 3;
  int r = t & (R - 1);      // R power of two
  int kb = t / R;
  int k = kb * 8 + k7;
  int row = PERM ? ((r & 3) * 512 + (r >> 2)) : r;
  dst[i] = (_Float16)src[(size_t)row * src_ld + c0 + k];
}

// ---------------- count-embed MLP (fp32) ----------------
__global__ __launch_bounds__(128)
void count_embed_k(const float* __restrict__ cv, const float* __restrict__ w1,
                   const float* __restrict__ b1, const float* __restrict__ w2,
                   const float* __restrict__ b2, float* __restrict__ ce) {
  const int b = blockIdx.x, tid = threadIdx.x;
  __shared__ float s_cv[CV_], s_h[CD_];
  if (tid < CV_) s_cv[tid] = cv[b * CV_ + tid];
  __syncthreads();
  float acc = b1[tid];
  for (int k = 0; k < CV_; ++k) acc += s_cv[k] * w1[tid * CV_ + k];
  s_h[tid] = fmaxf(acc, 0.f);
  __syncthreads();
  float acc2 = b2[tid];
  for (int k = 0; k < CD_; ++k) acc2 += s_h[k] * w2[tid * CD_ + k];
  ce[b * CD_ + tid] = acc2;
}

// ---------------- gather word embeddings -> fp16 (B*T, E) ----------------
__global__ __launch_bounds__(128)
void gather_we(const int* __restrict__ captions, const float* __restrict__ embed_w,
               _Float16* __restrict__ we_h) {
  const int r = blockIdx.x;
  const int b = r / T_, t = r - b * T_;
  const int idx = captions[b * LCAP_ + t];
  const float4 v = ((const float4*)(embed_w + (size_t)idx * E_))[threadIdx.x];
  h4v o = { (_Float16)v.x, (_Float16)v.y, (_Float16)v.z, (_Float16)v.w };
  ((h4v*)(we_h + (size_t)r * E_))[threadIdx.x] = o;
}

// ================= persistent per-batch sequential loop =================
// 128 blocks (one per b) x 512 threads, no occupancy constraint -> no spill.
// Thread tid owns j = tid with all 4 gates (permuted layout p = 4j+q).
// attproj[b] in LDS; attW[b] streamed from L2 each step (it is L2-resident);
// whh/atthw streamed with 8-deep ping-pong register prefetch.
__global__ __launch_bounds__(512)
void seq_loop(const _Float16* __restrict__ fcfeat_h,   // B x F
              const _Float16* __restrict__ fcproj_k,   // ki8 R=512 K=F (+pad)
              const float* __restrict__ fcproj_b,
              const _Float16* __restrict__ wcnt_k,     // ki8 R=2048(perm) K=CD (+pad)
              const float* __restrict__ ce,            // B x CD f32
              const float* __restrict__ b_ih, const float* __restrict__ b_hh,
              const _Float16* __restrict__ atthw_k,    // ki8 R=512 K=512 (+pad)
              const float* __restrict__ att_hb,
              const _Float16* __restrict__ attproj_h,  // B x 49 x 512
              const float* __restrict__ alpha_w, const float* __restrict__ alpha_b,
              const _Float16* __restrict__ attWp,      // B x 49 x 2048 (perm cols)
              const float* __restrict__ we_proj,       // (B*T) x 2048 (perm cols) f32
              const _Float16* __restrict__ whh_k,      // ki8 R=2048(perm) K=512 (+pad)
              _Float16* __restrict__ H_all_h,          // (B*T) x 512
              float* __restrict__ out_alpha) {         // B x T x 49
  const int b = blockIdx.x, tid = threadIdx.x;
  __shared__ _Float16 s_ap[NN_ * A_];      // 50 KB (prologue: fcfeat in first 4KB)
  __shared__ _Float16 s_h[H_];
  __shared__ _Float16 s_ceh[CD_];
  __shared__ float    s_hp[A_];
  __shared__ float    s_sc[64];
  __shared__ float    s_alpha[64];
  const int wv = tid >> 6, lane = tid & 63;

  // ---- prologue ----
  for (int i = tid; i < F_ / 2; i += 512)
    ((uint*)s_ap)[i] = ((const uint*)(fcfeat_h + (size_t)b * F_))[i];
  if (tid < CD_) s_ceh[tid] = (_Float16)ce[b * CD_ + tid];
  float aw8[8];
#pragma unroll
  for (int i = 0; i < 8; ++i) aw8[i] = alpha_w[lane * 8 + i];
  const float ab  = alpha_b[0];
  const float ahb = att_hb[tid];
  __syncthreads();

  // h0[tid] = tanh(fcfeat . fcproj[tid] + b)  (8-deep ping-pong prefetch)
  float c_state = 0.f;
  {
    float acc = fcproj_b[tid];
    const h8v* hv = (const h8v*)s_ap;       // fcfeat
    const h8v* wf = (const h8v*)fcproj_k + tid;
    h8v F0 = wf[0*512], F1 = wf[1*512], F2 = wf[2*512], F3 = wf[3*512];
    h8v G0, G1, G2, G3;
#pragma unroll
    for (int k8 = 0; k8 < 256; k8 += 8) {
      G0 = wf[(size_t)(k8+4)*512]; G1 = wf[(size_t)(k8+5)*512];
      G2 = wf[(size_t)(k8+6)*512]; G3 = wf[(size_t)(k8+7)*512];
      acc = dot8(hv[k8+0], F0, acc); acc = dot8(hv[k8+1], F1, acc);
      acc = dot8(hv[k8+2], F2, acc); acc = dot8(hv[k8+3], F3, acc);
      F0 = wf[(size_t)(k8+8)*512];  F1 = wf[(size_t)(k8+9)*512];
      F2 = wf[(size_t)(k8+10)*512]; F3 = wf[(size_t)(k8+11)*512];
      acc = dot8(hv[k8+4], G0, acc); acc = dot8(hv[k8+5], G1, acc);
      acc = dot8(hv[k8+6], G2, acc); acc = dot8(hv[k8+7], G3, acc);
    }
    s_h[tid] = (_Float16)tanh_f(acc);
  }
  // base[q] = b_ih + b_hh + ce . wcnt (gate q, j=tid)
  float base0 = b_ih[tid] + b_hh[tid];
  float base1 = b_ih[512 + tid] + b_hh[512 + tid];
  float base2 = b_ih[1024 + tid] + b_hh[1024 + tid];
  float base3 = b_ih[1536 + tid] + b_hh[1536 + tid];
  {
    const h8v* cv8 = (const h8v*)s_ceh;
    const h8v* wc = (const h8v*)wcnt_k + 4 * tid;
#pragma unroll
    for (int k8 = 0; k8 < 16; ++k8) {
      const h8v x = cv8[k8];
      const size_t o = (size_t)k8 * G4_;
      base0 = dot8(x, wc[o],     base0);
      base1 = dot8(x, wc[o + 1], base1);
      base2 = dot8(x, wc[o + 2], base2);
      base3 = dot8(x, wc[o + 3], base3);
    }
  }
  __syncthreads();     // all s_ap(fcfeat) reads done; s_h ready
  {
    const uint* src = (const uint*)(attproj_h + (size_t)b * NN_ * A_);
    for (int i = tid; i < NN_ * A_ / 2; i += 512) ((uint*)s_ap)[i] = src[i];
  }
  __syncthreads();

  const h8v* wa = (const h8v*)atthw_k + tid;
  const h8v* w8 = (const h8v*)whh_k + 4 * tid;
  const _Float16* awb = attWp + (size_t)b * NN_ * G4_ + 4 * tid;

  for (int t = 0; t < T_; ++t) {
    // ---- A: hp[tid] = att_hb + h . att_hw[tid]  (8-deep ping-pong) ----
    {
      float acc = ahb;
      const h8v* hv = (const h8v*)s_h;
      h8v F0 = wa[0*512], F1 = wa[1*512], F2 = wa[2*512], F3 = wa[3*512];
      h8v G0, G1, G2, G3;
#pragma unroll
      for (int k8 = 0; k8 < 64; k8 += 8) {
        G0 = wa[(size_t)(k8+4)*512]; G1 = wa[(size_t)(k8+5)*512];
        G2 = wa[(size_t)(k8+6)*512]; G3 = wa[(size_t)(k8+7)*512];
        acc = dot8(hv[k8+0], F0, acc); acc = dot8(hv[k8+1], F1, acc);
        acc = dot8(hv[k8+2], F2, acc); acc = dot8(hv[k8+3], F3, acc);
        F0 = wa[(size_t)(k8+8)*512];  F1 = wa[(size_t)(k8+9)*512];
        F2 = wa[(size_t)(k8+10)*512]; F3 = wa[(size_t)(k8+11)*512];
        acc = dot8(hv[k8+4], G0, acc); acc = dot8(hv[k8+5], G1, acc);
        acc = dot8(hv[k8+6], G2, acc); acc = dot8(hv[k8+7], G3, acc);
      }
      s_hp[tid] = acc;
    }
    __syncthreads();
    // ---- B: scores[n] = sum_a tanh(attproj[n][a] + hp[a]) * aw[a] ----
    {
      float hp8[8];
#pragma unroll
      for (int i = 0; i < 8; ++i) hp8[i] = s_hp[lane * 8 + i];
      for (int q = 0; q < 7; ++q) {
        const int n = wv + 8 * q;
        if (n >= NN_) break;
        const h8v apv = *(const h8v*)&s_ap[n * A_ + lane * 8];
        float s = 0.f;
#pragma unroll
        for (int i = 0; i < 8; ++i) {
          const float x = (float)apv[i] + hp8[i];
          const float e = __expf(2.f * fminf(fmaxf(x, -15.f), 15.f));
          s += __fdividef(e - 1.f, e + 1.f) * aw8[i];
        }
#pragma unroll
        for (int off = 32; off > 0; off >>= 1) s += __shfl_xor(s, off);
        if (lane == 0) s_sc[n] = s + ab;
      }
    }
    __syncthreads();
    // ---- C: softmax over 49 (wave 0) ----
    if (wv == 0) {
      float v = (lane < NN_) ? s_sc[lane] : -3.0e38f;
      float m = v;
#pragma unroll
      for (int off = 32; off > 0; off >>= 1) m = fmaxf(m, __shfl_xor(m, off));
      float e = (lane < NN_) ? __expf(v - m) : 0.f;
      float ssum = e;
#pragma unroll
      for (int off = 32; off > 0; off >>= 1) ssum += __shfl_xor(ssum, off);
      const float a = __fdividef(e, ssum);
      if (lane < NN_) {
        s_alpha[lane] = a;
        out_alpha[((size_t)b * T_ + t) * NN_ + lane] = a;
      }
    }
    __syncthreads();
    // ---- D: gates(j=tid) = base + we_proj + alpha@attW(L2 stream) + h@whh(prefetched) ----
    float a0, a1, a2, a3;
    {
      const float4 wp4 = *(const float4*)(we_proj + ((size_t)b * T_ + t) * G4_ + 4 * tid);
      a0 = base0 + wp4.x; a1 = base1 + wp4.y; a2 = base2 + wp4.z; a3 = base3 + wp4.w;
      // alpha @ attW : 49 independent coalesced 8B loads (L2-resident), unrolled
#pragma unroll
      for (int n = 0; n < NN_; ++n) {
        const h4v w = *(const h4v*)(awb + (size_t)n * G4_);
        const float al = s_alpha[n];
        a0 += al * (float)w[0]; a1 += al * (float)w[1];
        a2 += al * (float)w[2]; a3 += al * (float)w[3];
      }
      const h8v* hv = (const h8v*)s_h;
      h8v P0 = w8[0], P1 = w8[1], P2 = w8[2], P3 = w8[3];
      h8v Q0, Q1, Q2, Q3;
#pragma unroll
      for (int k8 = 0; k8 < 64; k8 += 2) {
        const size_t o1 = (size_t)(k8 + 1) * G4_;
        Q0 = w8[o1]; Q1 = w8[o1 + 1]; Q2 = w8[o1 + 2]; Q3 = w8[o1 + 3];
        const h8v x = hv[k8];
        a0 = dot8(x, P0, a0); a1 = dot8(x, P1, a1);
        a2 = dot8(x, P2, a2); a3 = dot8(x, P3, a3);
        const size_t o2 = (size_t)(k8 + 2) * G4_;
        P0 = w8[o2]; P1 = w8[o2 + 1]; P2 = w8[o2 + 2]; P3 = w8[o2 + 3];
        const h8v x2 = hv[k8 + 1];
        a0 = dot8(x2, Q0, a0); a1 = dot8(x2, Q1, a1);
        a2 = dot8(x2, Q2, a2); a3 = dot8(x2, Q3, a3);
      }
    }
    __syncthreads();   // all s_h reads done before overwrite
    // ---- E: LSTM cell (thread-local) ----
    {
      const float si = sig_f(a0), sf = sig_f(a1), so = sig_f(a3);
      c_state = sf * c_state + si * tanh_f(a2);
      const float hn = so * tanh_f(c_state);
      s_h[tid] = (_Float16)hn;
      H_all_h[((size_t)b * T_ + t) * H_ + tid] = (_Float16)hn;
    }
    __syncthreads();
  }
}

extern "C" void kernel_launch(void* const* d_in, const int* in_sizes, int n_in,
                              void* d_out, int out_size, void* d_ws, size_t ws_size,
                              hipStream_t stream) {
  const float* att_feats  = (const float*)d_in[0];
  const float* fc_feats   = (const float*)d_in[1];
  const int*   captions   = (const int*)  d_in[2];
  const float* count_vecs = (const float*)d_in[3];
  const float* embed_w    = (const float*)d_in[4];
  const float* cm_w1      = (const float*)d_in[5];
  const float* cm_b1      = (const float*)d_in[6];
  const float* cm_w2      = (const float*)d_in[7];
  const float* cm_b2      = (const float*)d_in[8];
  const float* att_hw     = (const float*)d_in[9];
  const float* att_hb     = (const float*)d_in[10];
  const float* att_fw     = (const float*)d_in[11];
  const float* att_fb     = (const float*)d_in[12];
  const float* alpha_w    = (const float*)d_in[13];
  const float* alpha_b    = (const float*)d_in[14];
  const float* fcproj_w   = (const float*)d_in[15];
  const float* fcproj_b   = (const float*)d_in[16];
  const float* w_ih       = (const float*)d_in[17];
  const float* b_ih       = (const float*)d_in[18];
  const float* w_hh       = (const float*)d_in[19];
  const float* b_hh       = (const float*)d_in[20];
  const float* fc_w       = (const float*)d_in[21];
  const float* fc_b       = (const float*)d_in[22];
  float* out = (float*)d_out;

  char* wsb = (char*)d_ws;
  size_t off = 0;
  auto nxt = [&](size_t bytes) { char* p = wsb + off; off += (bytes + 255) & ~(size_t)255; return p; };
  _Float16* att_th    = (_Float16*)nxt((size_t)B_*NN_*F_*2);
  _Float16* attW_h    = (_Float16*)nxt((size_t)B_*NN_*G4_*2);
  _Float16* attproj_h = (_Float16*)nxt((size_t)B_*NN_*A_*2);
  _Float16* we_h      = (_Float16*)nxt((size_t)B_*T_*E_*2);
  _Float16* H_all_h   = (_Float16*)nxt((size_t)B_*T_*H_*2);
  _Float16* w_ihF_h   = (_Float16*)nxt((size_t)G4_*F_*2);
  _Float16* w_ih0_h   = (_Float16*)nxt((size_t)G4_*E_*2);
  _Float16* fc_w_h    = (_Float16*)nxt((size_t)VP_*H_*2);
  _Float16* att_fw_h  = (_Float16*)nxt((size_t)A_*F_*2);
  _Float16* fcfeat_h  = (_Float16*)nxt((size_t)B_*F_*2);
  _Float16* whh_k     = (_Float16*)nxt((size_t)G4_*(H_+32)*2);  // pad for prefetch overshoot
  _Float16* atthw_k   = (_Float16*)nxt((size_t)A_*(H_+32)*2);
  _Float16* fcproj_k  = (_Float16*)nxt((size_t)H_*(F_+32)*2);
  _Float16* wcnt_k    = (_Float16*)nxt((size_t)G4_*(CD_+32)*2);
  float*    we_proj   = (float*)nxt((size_t)B_*T_*G4_*4);
  float*    ce        = (float*)nxt((size_t)B_*CD_*4);
  if (off > ws_size) return;

  const size_t ALPHA_OFF = (size_t)B_ * T_ * V_;

  // ---- packs & small precompute ----
  transpose_att<<<dim3(F_/64, B_), 256, 0, stream>>>(att_feats, att_th);
  pack_h16<0><<<((size_t)B_*F_ + 255)/256, 256, 0, stream>>>(fc_feats, F_, 0, fcfeat_h, F_, B_, B_);
  pack_h16<1><<<((size_t)G4_*F_ + 255)/256, 256, 0, stream>>>(w_ih, E_+F_+CD_, E_, w_ihF_h, F_, G4_, G4_);
  pack_h16<1><<<((size_t)G4_*E_ + 255)/256, 256, 0, stream>>>(w_ih, E_+F_+CD_, 0, w_ih0_h, E_, G4_, G4_);
  pack_h16<0><<<((size_t)A_*F_ + 255)/256, 256, 0, stream>>>(att_fw, F_, 0, att_fw_h, F_, A_, A_);
  pack_h16<0><<<((size_t)VP_*H_ + 255)/256, 256, 0, stream>>>(fc_w, H_, 0, fc_w_h, H_, V_, VP_);
  pack_ki8<1><<<((size_t)G4_*H_ + 255)/256, 256, 0, stream>>>(w_hh, H_, 0, whh_k, G4_, H_);
  pack_ki8<1><<<((size_t)G4_*CD_ + 255)/256, 256, 0, stream>>>(w_ih, E_+F_+CD_, E_+F_, wcnt_k, G4_, CD_);
  pack_ki8<0><<<((size_t)A_*H_ + 255)/256, 256, 0, stream>>>(att_hw, H_, 0, atthw_k, A_, H_);
  pack_ki8<0><<<((size_t)H_*F_ + 255)/256, 256, 0, stream>>>(fcproj_w, F_, 0, fcproj_k, H_, F_);
  count_embed_k<<<B_, 128, 0, stream>>>(count_vecs, cm_w1, cm_b1, cm_w2, cm_b2, ce);
  gather_we<<<B_ * T_, 128, 0, stream>>>(captions, embed_w, we_h);

  // ---- MFMA precompute GEMMs ----
  gemm_h16<1,1><<<dim3(A_/128, (B_*NN_)/128), 256, 0, stream>>>(
      att_th, F_, att_fw_h, F_, att_fb, attproj_h, A_, A_, F_);
  gemm_h16<1,0><<<dim3(G4_/128, (B_*NN_)/128), 256, 0, stream>>>(
      att_th, F_, w_ihF_h, F_, nullptr, attW_h, G4_, G4_, F_);
  gemm_h16<0,0><<<dim3(G4_/128, (B_*T_)/128), 256, 0, stream>>>(
      we_h, E_, w_ih0_h, E_, nullptr, we_proj, G4_, G4_, E_);

  // ---- persistent sequential loop ----
  seq_loop<<<B_, 512, 0, stream>>>(fcfeat_h, fcproj_k, fcproj_b,
                                   wcnt_k, ce, b_ih, b_hh,
                                   atthw_k, att_hb,
                                   attproj_h, alpha_w, alpha_b,
                                   attW_h, we_proj, whh_k,
                                   H_all_h, out + ALPHA_OFF);

  // ---- logits = H_all @ fc_w^T + fc_b -> out (B*T, V) ----
  gemm_h16<0,1><<<dim3(VP_/128, (B_*T_)/128), 256, 0, stream>>>(
      H_all_h, H_, fc_w_h, H_, fc_b, out, V_, V_, H_);
}

// Round 12
// 1838.342 us; speedup vs baseline: 3.9298x; 3.9298x over previous
//
#include <hip/hip_runtime.h>
#include <cstdint>

#define B_   128
#define T_   30
#define F_   2048
#define E_   512
#define H_   512
#define A_   512
#define CD_  128
#define CV_  64
#define V_   10000
#define VP_  10112
#define NN_  49
#define G4_  2048
#define LCAP_ 31

typedef __attribute__((ext_vector_type(4))) float f32x4;
typedef _Float16 h2v __attribute__((ext_vector_type(2)));
typedef _Float16 h4v __attribute__((ext_vector_type(4)));
typedef _Float16 h8v __attribute__((ext_vector_type(8)));

__device__ __forceinline__ float fdot2f(h2v a, h2v b, float c) {
#if __has_builtin(__builtin_amdgcn_fdot2)
  return __builtin_amdgcn_fdot2(a, b, c, false);
#else
  return c + (float)a[0]*(float)b[0] + (float)a[1]*(float)b[1];
#endif
}
__device__ __forceinline__ float dot8(h8v x, h8v w, float acc) {
  acc = fdot2f((h2v){x[0],x[1]}, (h2v){w[0],w[1]}, acc);
  acc = fdot2f((h2v){x[2],x[3]}, (h2v){w[2],w[3]}, acc);
  acc = fdot2f((h2v){x[4],x[5]}, (h2v){w[4],w[5]}, acc);
  acc = fdot2f((h2v){x[6],x[7]}, (h2v){w[6],w[7]}, acc);
  return acc;
}
__device__ __forceinline__ float tanh_f(float x) {
  x = fminf(fmaxf(x, -15.f), 15.f);
  float e = __expf(2.f * x);
  return __fdividef(e - 1.f, e + 1.f);
}
__device__ __forceinline__ float sig_f(float x) {
  return __fdividef(1.f, 1.f + __expf(-x));
}

// ================= fp16 MFMA GEMM: C = A(M,K) @ B(N,K)^T (+bias) =================
template<int OUT_H, int BIAS>
__global__ __launch_bounds__(256)
void gemm_h16(const _Float16* __restrict__ A, int lda,
              const _Float16* __restrict__ B, int ldb,
              const float* __restrict__ bias,
              void* __restrict__ Cv, int ldc, int Nreal, int K) {
  __shared__ _Float16 As[128 * 32];
  __shared__ _Float16 Bs[128 * 32];
  const int tid = threadIdx.x;
  const int m0 = blockIdx.y * 128, n0 = blockIdx.x * 128;
  const int lane = tid & 63, wid = tid >> 6;
  const int wm = (wid >> 1) * 64, wn = (wid & 1) * 64;
  f32x4 acc[4][4] = {};
  const int lr = tid >> 2;
  const int lc = (tid & 3) * 8;
  const _Float16* Ag  = A + (size_t)(m0 + lr) * lda + lc;
  const _Float16* Ag2 = Ag + (size_t)64 * lda;
  const _Float16* Bg  = B + (size_t)(n0 + lr) * ldb + lc;
  const _Float16* Bg2 = Bg + (size_t)64 * ldb;
  auto* lAs = (__attribute__((address_space(3))) char*)As;
  auto* lBs = (__attribute__((address_space(3))) char*)Bs;
  const int ldst = lr * 64 + (tid & 3) * 16;
  const int ar = wm + (lane & 15);
  const int br = wn + (lane & 15);
  const int kc = (lane >> 4) * 8;
  for (int k0 = 0; k0 < K; k0 += 32) {
    __builtin_amdgcn_global_load_lds((const __attribute__((address_space(1))) char*)(Ag  + k0), lAs + ldst,        16, 0, 0);
    __builtin_amdgcn_global_load_lds((const __attribute__((address_space(1))) char*)(Ag2 + k0), lAs + 4096 + ldst, 16, 0, 0);
    __builtin_amdgcn_global_load_lds((const __attribute__((address_space(1))) char*)(Bg  + k0), lBs + ldst,        16, 0, 0);
    __builtin_amdgcn_global_load_lds((const __attribute__((address_space(1))) char*)(Bg2 + k0), lBs + 4096 + ldst, 16, 0, 0);
    __syncthreads();
    h8v af[4], bfr[4];
#pragma unroll
    for (int i = 0; i < 4; ++i) {
      af[i]  = *(const h8v*)&As[(ar + i * 16) * 32 + kc];
      bfr[i] = *(const h8v*)&Bs[(br + i * 16) * 32 + kc];
    }
#pragma unroll
    for (int i = 0; i < 4; ++i)
#pragma unroll
      for (int j = 0; j < 4; ++j)
        acc[i][j] = __builtin_amdgcn_mfma_f32_16x16x32_f16(af[i], bfr[j], acc[i][j], 0, 0, 0);
    __syncthreads();
  }
  const int orow = m0 + wm + (lane >> 4) * 4;
  const int ocol = n0 + wn + (lane & 15);
#pragma unroll
  for (int j = 0; j < 4; ++j) {
    const int col = ocol + j * 16;
    if (col >= Nreal) continue;
    const float bv = BIAS ? bias[col] : 0.f;
#pragma unroll
    for (int i = 0; i < 4; ++i) {
#pragma unroll
      for (int r = 0; r < 4; ++r) {
        const int row = orow + i * 16 + r;
        const float v = acc[i][j][r] + bv;
        if (OUT_H) ((_Float16*)Cv)[(size_t)row * ldc + col] = (_Float16)v;
        else       ((float*)Cv)[(size_t)row * ldc + col] = v;
      }
    }
  }
}

// ---------------- att_feats (B,F,49) -> att_th (B,49,F) fp16 ----------------
__global__ __launch_bounds__(256)
void transpose_att(const float* __restrict__ af, _Float16* __restrict__ att_th) {
  __shared__ float s[64 * NN_];
  const int b = blockIdx.y, f0 = blockIdx.x * 64;
  const float* src = af + (size_t)b * F_ * NN_ + (size_t)f0 * NN_;
  for (int i = threadIdx.x; i < 64 * NN_; i += 256) s[i] = src[i];
  __syncthreads();
  _Float16* dst = att_th + (size_t)b * NN_ * F_ + f0;
  for (int i = threadIdx.x; i < NN_ * 64; i += 256) {
    int n = i >> 6, j = i & 63;
    dst[(size_t)n * F_ + j] = (_Float16)s[j * NN_ + n];
  }
}

// ---------------- fp32 (strided cols) -> packed fp16, row pad ----------------
__global__ void pack_h16(const float* __restrict__ src, int src_ld, int c0,
                         _Float16* __restrict__ dst, int C, int R, int Rpad) {
  int i = blockIdx.x * 256 + threadIdx.x;
  if (i >= Rpad * C) return;
  int r = i / C, c = i - r * C;
  float v = (r < R) ? src[(size_t)r * src_ld + c0 + c] : 0.f;
  dst[i] = (_Float16)v;
}

// ---------------- fp32 -> fp16 k-interleaved: dst[(k/8)*R*8 + r*8 + k%8] ----------------
__global__ void pack_ki8(const float* __restrict__ src, int src_ld, int c0,
                         _Float16* __restrict__ dst, int R, int K) {
  int i = blockIdx.x * 256 + threadIdx.x;
  if (i >= R * K) return;
  int k7 = i & 7;
  int t = i >> 3;
  int r = t & (R - 1);      // R power of two
  int kb = t / R;
  int k = kb * 8 + k7;
  dst[i] = (_Float16)src[(size_t)r * src_ld + c0 + k];
}

// ---------------- count-embed MLP (fp32) ----------------
__global__ __launch_bounds__(128)
void count_embed_k(const float* __restrict__ cv, const float* __restrict__ w1,
                   const float* __restrict__ b1, const float* __restrict__ w2,
                   const float* __restrict__ b2, float* __restrict__ ce) {
  const int b = blockIdx.x, tid = threadIdx.x;
  __shared__ float s_cv[CV_], s_h[CD_];
  if (tid < CV_) s_cv[tid] = cv[b * CV_ + tid];
  __syncthreads();
  float acc = b1[tid];
  for (int k = 0; k < CV_; ++k) acc += s_cv[k] * w1[tid * CV_ + k];
  s_h[tid] = fmaxf(acc, 0.f);
  __syncthreads();
  float acc2 = b2[tid];
  for (int k = 0; k < CD_; ++k) acc2 += s_h[k] * w2[tid * CD_ + k];
  ce[b * CD_ + tid] = acc2;
}

// ---------------- gather word embeddings -> fp16 (B*T, E) ----------------
__global__ __launch_bounds__(128)
void gather_we(const int* __restrict__ captions, const float* __restrict__ embed_w,
               _Float16* __restrict__ we_h) {
  const int r = blockIdx.x;
  const int b = r / T_, t = r - b * T_;
  const int idx = captions[b * LCAP_ + t];
  const float4 v = ((const float4*)(embed_w + (size_t)idx * E_))[threadIdx.x];
  h4v o = { (_Float16)v.x, (_Float16)v.y, (_Float16)v.z, (_Float16)v.w };
  ((h4v*)(we_h + (size_t)r * E_))[threadIdx.x] = o;
}

// ================= persistent per-batch sequential loop =================
// 128 blocks (one per b) x 1024 threads.
// attproj[b] lives in LDS (50KB, loaded once); attW[b] columns live in registers
// (each thread owns gate pair p = {2tid, 2tid+1}); whh/atthw stream from L2.
__global__ __launch_bounds__(1024)
void seq_loop(const _Float16* __restrict__ fcfeat_h,   // B x F
              const _Float16* __restrict__ fcproj_k,   // ki8 R=512 K=F
              const float* __restrict__ fcproj_b,
              const _Float16* __restrict__ wcnt_h,     // 2048 x CD
              const float* __restrict__ ce,            // B x CD f32
              const float* __restrict__ b_ih, const float* __restrict__ b_hh,
              const _Float16* __restrict__ atthw_k,    // ki8 R=512 K=512
              const float* __restrict__ att_hb,
              const _Float16* __restrict__ attproj_h,  // B x 49 x 512
              const float* __restrict__ alpha_w, const float* __restrict__ alpha_b,
              const _Float16* __restrict__ attW_h,     // B x 49 x 2048
              const float* __restrict__ we_proj,       // (B*T) x 2048 f32
              const _Float16* __restrict__ whh_k,      // ki8 R=2048 K=512
              _Float16* __restrict__ H_all_h,          // (B*T) x 512
              float* __restrict__ out_alpha) {         // B x T x 49
  const int b = blockIdx.x, tid = threadIdx.x;
  __shared__ _Float16 s_ap[NN_ * A_];      // 50 KB: attproj[b] (+att_fb)
  __shared__ _Float16 s_h[H_];             // 1 KB
  __shared__ float    s_hp2[2][A_];        // 4 KB
  __shared__ _Float16 s_gates[G4_];        // 4 KB (fp16 gate pre-acts; prologue: fcfeat)
  __shared__ float    s_sc[64];
  __shared__ float    s_alpha[64];
  __shared__ float    s_ce[CD_];

  const int a9 = tid & 511, half = tid >> 9;
  const int wv = tid >> 6, lane = tid & 63;

  // ---- prologue: fill LDS ----
  // fcfeat (2048 halves) into s_gates area (4 KB)
  ((uint*)s_gates)[tid] = ((const uint*)(fcfeat_h + (size_t)b * F_))[tid];
  // attproj[b]: 49*512 halves = 12544 uints
  {
    const uint* src = (const uint*)(attproj_h + (size_t)b * NN_ * A_);
    for (int i = tid; i < NN_ * A_ / 2; i += 1024) ((uint*)s_ap)[i] = src[i];
  }
  if (tid < CD_) s_ce[tid] = ce[b * CD_ + tid];
  // attW columns for this thread's gate pair -> registers
  h2v aW[NN_];
  {
    const _Float16* base = attW_h + (size_t)b * NN_ * G4_ + 2 * tid;
#pragma unroll
    for (int n = 0; n < NN_; ++n) aW[n] = *(const h2v*)(base + (size_t)n * G4_);
  }
  float aw8[8];
#pragma unroll
  for (int i = 0; i < 8; ++i) aw8[i] = alpha_w[lane * 8 + i];
  const float ab  = alpha_b[0];
  const float ahb = (half == 0) ? att_hb[a9] : 0.f;
  __syncthreads();

  // h0 (threads 0..511): tanh(fcfeat . fcproj + b)
  float c_state = 0.f;
  if (tid < H_) {
    float acc = fcproj_b[tid];
    const h8v* xv = (const h8v*)s_gates;   // fcfeat lives here
    const h8v* wp = (const h8v*)fcproj_k;
    for (int k8 = 0; k8 < F_ / 8; ++k8)
      acc = dot8(xv[k8], wp[(size_t)k8 * 512 + tid], acc);
    s_h[tid] = (_Float16)tanh_f(acc);
  }
  // base for gate pair p = {2tid, 2tid+1}: b_ih + b_hh + ce . wcnt[p]
  float base0 = b_ih[2 * tid]     + b_hh[2 * tid];
  float base1 = b_ih[2 * tid + 1] + b_hh[2 * tid + 1];
  {
    const h8v* w0 = (const h8v*)(wcnt_h + (size_t)(2 * tid) * CD_);
    const h8v* w1 = (const h8v*)(wcnt_h + (size_t)(2 * tid + 1) * CD_);
#pragma unroll
    for (int k8 = 0; k8 < CD_ / 8; ++k8) {
      const h8v a = w0[k8], c = w1[k8];
#pragma unroll
      for (int i = 0; i < 8; ++i) {
        const float cv = s_ce[k8 * 8 + i];
        base0 += cv * (float)a[i];
        base1 += cv * (float)c[i];
      }
    }
  }
  __syncthreads();   // s_h ready; fcfeat area free for gates

  const h8v* atthw8 = (const h8v*)atthw_k;
  const h8v* whh8   = (const h8v*)whh_k;

  for (int t = 0; t < T_; ++t) {
    // ---- A: hp[a] = att_hb[a] + h . att_hw[a]  (split K across halves) ----
    {
      float acc = ahb;
      const h8v* hv = (const h8v*)s_h;
      const int k80 = half * 32;
#pragma unroll 8
      for (int k8 = k80; k8 < k80 + 32; ++k8)
        acc = dot8(hv[k8], atthw8[(size_t)k8 * 512 + a9], acc);
      s_hp2[half][a9] = acc;
    }
    __syncthreads();
    // ---- B: scores[n] = sum_a tanh(attproj[n][a] + hp[a]) * aw[a] ----
    {
      float hp8[8];
#pragma unroll
      for (int i = 0; i < 8; ++i) {
        const int a = lane * 8 + i;
        hp8[i] = s_hp2[0][a] + s_hp2[1][a];
      }
      const int Q = (wv == 0) ? 4 : 3;
      for (int q = 0; q < Q; ++q) {
        const int n = wv + 16 * q;
        const h8v apv = *(const h8v*)&s_ap[n * A_ + lane * 8];
        float s = 0.f;
#pragma unroll
        for (int i = 0; i < 8; ++i) {
          const float x = (float)apv[i] + hp8[i];
          const float e = __expf(2.f * fminf(fmaxf(x, -15.f), 15.f));
          s += __fdividef(e - 1.f, e + 1.f) * aw8[i];
        }
#pragma unroll
        for (int off = 32; off > 0; off >>= 1) s += __shfl_xor(s, off);
        if (lane == 0) s_sc[n] = s + ab;
      }
    }
    __syncthreads();
    // ---- C: softmax over 49 (wave 0) ----
    if (wv == 0) {
      float v = (lane < NN_) ? s_sc[lane] : -3.0e38f;
      float m = v;
#pragma unroll
      for (int off = 32; off > 0; off >>= 1) m = fmaxf(m, __shfl_xor(m, off));
      float e = (lane < NN_) ? __expf(v - m) : 0.f;
      float ssum = e;
#pragma unroll
      for (int off = 32; off > 0; off >>= 1) ssum += __shfl_xor(ssum, off);
      const float a = __fdividef(e, ssum);
      if (lane < NN_) {
        s_alpha[lane] = a;
        out_alpha[((size_t)b * T_ + t) * NN_ + lane] = a;
      }
    }
    __syncthreads();
    // ---- D: gate pair = base + we_proj + alpha@attW(reg) + h@whh(L2 stream) ----
    {
      const float2 wp = *(const float2*)(we_proj + ((size_t)b * T_ + t) * G4_ + 2 * tid);
      float acc0 = base0 + wp.x, acc1 = base1 + wp.y;
#pragma unroll
      for (int n = 0; n < NN_; ++n) {
        const float al = s_alpha[n];
        acc0 += al * (float)aW[n][0];
        acc1 += al * (float)aW[n][1];
      }
      const h8v* hv = (const h8v*)s_h;
#pragma unroll 4
      for (int k8 = 0; k8 < H_ / 8; ++k8) {
        const h8v x = hv[k8];
        acc0 = dot8(x, whh8[(size_t)k8 * G4_ + 2 * tid],     acc0);
        acc1 = dot8(x, whh8[(size_t)k8 * G4_ + 2 * tid + 1], acc1);
      }
      *(h2v*)&s_gates[2 * tid] = (h2v){ (_Float16)acc0, (_Float16)acc1 };
    }
    __syncthreads();
    // ---- E: LSTM cell (threads 0..511) ----
    if (tid < H_) {
      const int j = tid;
      const float gi = (float)s_gates[j];
      const float gf = (float)s_gates[512 + j];
      const float gg = (float)s_gates[1024 + j];
      const float go = (float)s_gates[1536 + j];
      const float si = sig_f(gi), sf = sig_f(gf), so = sig_f(go);
      c_state = sf * c_state + si * tanh_f(gg);
      const float hn = so * tanh_f(c_state);
      s_h[j] = (_Float16)hn;
      H_all_h[((size_t)b * T_ + t) * H_ + j] = (_Float16)hn;
    }
    __syncthreads();
  }
}

extern "C" void kernel_launch(void* const* d_in, const int* in_sizes, int n_in,
                              void* d_out, int out_size, void* d_ws, size_t ws_size,
                              hipStream_t stream) {
  const float* att_feats  = (const float*)d_in[0];
  const float* fc_feats   = (const float*)d_in[1];
  const int*   captions   = (const int*)  d_in[2];
  const float* count_vecs = (const float*)d_in[3];
  const float* embed_w    = (const float*)d_in[4];
  const float* cm_w1      = (const float*)d_in[5];
  const float* cm_b1      = (const float*)d_in[6];
  const float* cm_w2      = (const float*)d_in[7];
  const float* cm_b2      = (const float*)d_in[8];
  const float* att_hw     = (const float*)d_in[9];
  const float* att_hb     = (const float*)d_in[10];
  const float* att_fw     = (const float*)d_in[11];
  const float* att_fb     = (const float*)d_in[12];
  const float* alpha_w    = (const float*)d_in[13];
  const float* alpha_b    = (const float*)d_in[14];
  const float* fcproj_w   = (const float*)d_in[15];
  const float* fcproj_b   = (const float*)d_in[16];
  const float* w_ih       = (const float*)d_in[17];
  const float* b_ih       = (const float*)d_in[18];
  const float* w_hh       = (const float*)d_in[19];
  const float* b_hh       = (const float*)d_in[20];
  const float* fc_w       = (const float*)d_in[21];
  const float* fc_b       = (const float*)d_in[22];
  float* out = (float*)d_out;

  char* wsb = (char*)d_ws;
  size_t off = 0;
  auto nxt = [&](size_t bytes) { char* p = wsb + off; off += (bytes + 255) & ~(size_t)255; return p; };
  _Float16* att_th    = (_Float16*)nxt((size_t)B_*NN_*F_*2);
  _Float16* attW_h    = (_Float16*)nxt((size_t)B_*NN_*G4_*2);
  _Float16* attproj_h = (_Float16*)nxt((size_t)B_*NN_*A_*2);
  _Float16* we_h      = (_Float16*)nxt((size_t)B_*T_*E_*2);
  _Float16* H_all_h   = (_Float16*)nxt((size_t)B_*T_*H_*2);
  _Float16* w_ihF_h   = (_Float16*)nxt((size_t)G4_*F_*2);
  _Float16* w_ih0_h   = (_Float16*)nxt((size_t)G4_*E_*2);
  _Float16* wcnt_h    = (_Float16*)nxt((size_t)G4_*CD_*2);
  _Float16* fc_w_h    = (_Float16*)nxt((size_t)VP_*H_*2);
  _Float16* att_fw_h  = (_Float16*)nxt((size_t)A_*F_*2);
  _Float16* fcfeat_h  = (_Float16*)nxt((size_t)B_*F_*2);
  _Float16* whh_k     = (_Float16*)nxt((size_t)G4_*H_*2);
  _Float16* atthw_k   = (_Float16*)nxt((size_t)A_*H_*2);
  _Float16* fcproj_k  = (_Float16*)nxt((size_t)H_*F_*2);
  float*    we_proj   = (float*)nxt((size_t)B_*T_*G4_*4);
  float*    ce        = (float*)nxt((size_t)B_*CD_*4);
  if (off > ws_size) return;

  const size_t ALPHA_OFF = (size_t)B_ * T_ * V_;

  // ---- packs & small precompute ----
  transpose_att<<<dim3(F_/64, B_), 256, 0, stream>>>(att_feats, att_th);
  pack_h16<<<((size_t)B_*F_ + 255)/256, 256, 0, stream>>>(fc_feats, F_, 0, fcfeat_h, F_, B_, B_);
  pack_h16<<<((size_t)G4_*F_ + 255)/256, 256, 0, stream>>>(w_ih, E_+F_+CD_, E_, w_ihF_h, F_, G4_, G4_);
  pack_h16<<<((size_t)G4_*E_ + 255)/256, 256, 0, stream>>>(w_ih, E_+F_+CD_, 0, w_ih0_h, E_, G4_, G4_);
  pack_h16<<<((size_t)G4_*CD_ + 255)/256, 256, 0, stream>>>(w_ih, E_+F_+CD_, E_+F_, wcnt_h, CD_, G4_, G4_);
  pack_h16<<<((size_t)A_*F_ + 255)/256, 256, 0, stream>>>(att_fw, F_, 0, att_fw_h, F_, A_, A_);
  pack_h16<<<((size_t)VP_*H_ + 255)/256, 256, 0, stream>>>(fc_w, H_, 0, fc_w_h, H_, V_, VP_);
  pack_ki8<<<((size_t)G4_*H_ + 255)/256, 256, 0, stream>>>(w_hh, H_, 0, whh_k, G4_, H_);
  pack_ki8<<<((size_t)A_*H_ + 255)/256, 256, 0, stream>>>(att_hw, H_, 0, atthw_k, A_, H_);
  pack_ki8<<<((size_t)H_*F_ + 255)/256, 256, 0, stream>>>(fcproj_w, F_, 0, fcproj_k, H_, F_);
  count_embed_k<<<B_, 128, 0, stream>>>(count_vecs, cm_w1, cm_b1, cm_w2, cm_b2, ce);
  gather_we<<<B_ * T_, 128, 0, stream>>>(captions, embed_w, we_h);

  // ---- MFMA precompute GEMMs ----
  gemm_h16<1,1><<<dim3(A_/128, (B_*NN_)/128), 256, 0, stream>>>(
      att_th, F_, att_fw_h, F_, att_fb, attproj_h, A_, A_, F_);
  gemm_h16<1,0><<<dim3(G4_/128, (B_*NN_)/128), 256, 0, stream>>>(
      att_th, F_, w_ihF_h, F_, nullptr, attW_h, G4_, G4_, F_);
  gemm_h16<0,0><<<dim3(G4_/128, (B_*T_)/128), 256, 0, stream>>>(
      we_h, E_, w_ih0_h, E_, nullptr, we_proj, G4_, G4_, E_);

  // ---- persistent sequential loop ----
  seq_loop<<<B_, 1024, 0, stream>>>(fcfeat_h, fcproj_k, fcproj_b,
                                    wcnt_h, ce, b_ih, b_hh,
                                    atthw_k, att_hb,
                                    attproj_h, alpha_w, alpha_b,
                                    attW_h, we_proj, whh_k,
                                    H_all_h, out + ALPHA_OFF);

  // ---- logits = H_all @ fc_w^T + fc_b -> out (B*T, V) ----
  gemm_h16<0,1><<<dim3(VP_/128, (B_*T_)/128), 256, 0, stream>>>(
      H_all_h, H_, fc_w_h, H_, fc_b, out, V_, V_, H_);
}